// Round 1
// baseline (927.973 us; speedup 1.0000x reference)
//
#include <hip/hip_runtime.h>
#include <hip/hip_bf16.h>
#include <math.h>

#define N_NODES 50000
#define N_EDGES 800000
#define NH 4

// ---------------- CSR build ----------------

__global__ void k_hist(const int* __restrict__ dst, int* __restrict__ deg) {
    int i = blockIdx.x * 256 + threadIdx.x;
    if (i < N_EDGES) atomicAdd(&deg[dst[i]], 1);
}

__global__ __launch_bounds__(1024) void k_scan1(const int* __restrict__ deg,
                                                int* __restrict__ offs,
                                                int* __restrict__ bsum) {
    __shared__ int tmp[1024];
    int b = blockIdx.x, t = threadIdx.x;
    int i = b * 1024 + t;
    int v = (i < N_NODES) ? deg[i] : 0;
    tmp[t] = v;
    __syncthreads();
    for (int off = 1; off < 1024; off <<= 1) {
        int add = (t >= off) ? tmp[t - off] : 0;
        __syncthreads();
        tmp[t] += add;
        __syncthreads();
    }
    if (i < N_NODES) offs[i] = tmp[t] - v;   // exclusive within block
    if (t == 1023) bsum[b] = tmp[t];
}

__global__ void k_scan2(int* __restrict__ bsum, int nb) {
    if (blockIdx.x == 0 && threadIdx.x == 0) {
        int run = 0;
        for (int b = 0; b < nb; ++b) { int v = bsum[b]; bsum[b] = run; run += v; }
    }
}

__global__ __launch_bounds__(1024) void k_scan3(int* __restrict__ offs,
                                                const int* __restrict__ bsum,
                                                int* __restrict__ cursor) {
    int b = blockIdx.x, t = threadIdx.x;
    int i = b * 1024 + t;
    if (i < N_NODES) {
        int o = offs[i] + bsum[b];
        offs[i] = o;
        cursor[i] = o;
    }
    if (b == 0 && t == 0) offs[N_NODES] = N_EDGES;
}

__global__ void k_scatter(const int* __restrict__ src, const int* __restrict__ dst,
                          int* __restrict__ cursor, int* __restrict__ csrc) {
    int i = blockIdx.x * 256 + threadIdx.x;
    if (i < N_EDGES) {
        int p = atomicAdd(&cursor[dst[i]], 1);
        csrc[p] = src[i];
    }
}

// ---------------- GEMM + attention dots ----------------
// feat = h @ W  ([N,K]x[K,NOUT]); el[n,h] = sum_d feat*al, er likewise.
template <int K, int NOUT, int NT, int DH>
__global__ __launch_bounds__(NT) void gemm_feat(const float* __restrict__ hin,
                                                const float* __restrict__ W,
                                                const float* __restrict__ al,
                                                const float* __restrict__ ar,
                                                float* __restrict__ feat,
                                                float* __restrict__ el,
                                                float* __restrict__ er) {
    __shared__ float hrow[K];
    __shared__ float frow[NOUT];
    int n = blockIdx.x;
    int tid = threadIdx.x;
    for (int k = tid; k < K; k += NT) hrow[k] = hin[(size_t)n * K + k];
    __syncthreads();
    if (tid < NOUT) {
        float acc = 0.f;
#pragma unroll 4
        for (int k = 0; k < K; ++k) acc = fmaf(hrow[k], W[(size_t)k * NOUT + tid], acc);
        feat[(size_t)n * NOUT + tid] = acc;
        frow[tid] = acc;
    }
    __syncthreads();
    if (tid < 2 * NH) {
        int h = tid >> 1;
        const float* av = (tid & 1) ? ar : al;
        float s = 0.f;
        for (int d = 0; d < DH; ++d) s = fmaf(frow[h * DH + d], av[h * DH + d], s);
        if (tid & 1) er[n * NH + h] = s;
        else         el[n * NH + h] = s;
    }
}

// ---------------- aggregation, layers 1-2 (NOUT=128) ----------------
// one wave per dst node; lane owns float2 at flat index 2*lane; head = lane>>4.
__global__ __launch_bounds__(256) void gat_agg128(const float* __restrict__ feat,
                                                  const float* __restrict__ el,
                                                  const float* __restrict__ er,
                                                  const int* __restrict__ offs,
                                                  const int* __restrict__ csrc,
                                                  float* __restrict__ out) {
    int wave = threadIdx.x >> 6;
    int lane = threadIdx.x & 63;
    int n = blockIdx.x * 4 + wave;
    int h = lane >> 4;
    float erh = er[n * NH + h];
    int i0 = offs[n], i1 = offs[n + 1];
    float m = -__builtin_inff(), s = 0.f, ax = 0.f, ay = 0.f;
    for (int i = i0; i < i1; ++i) {
        int src = csrc[i];
        float2 v = *reinterpret_cast<const float2*>(feat + (size_t)src * 128 + 2 * lane);
        float e = el[src * NH + h] + erh;
        e = e >= 0.f ? e : 0.2f * e;
        float mn = fmaxf(m, e);
        float sc = __expf(m - mn);
        float p = __expf(e - mn);
        s = s * sc + p;
        ax = fmaf(p, v.x, ax * sc);
        ay = fmaf(p, v.y, ay * sc);
        m = mn;
    }
    float inv = (s > 0.f) ? 1.f / s : 0.f;
    float ox = ax * inv, oy = ay * inv;
    // ELU
    ox = ox > 0.f ? ox : expm1f(ox);
    oy = oy > 0.f ? oy : expm1f(oy);
    *reinterpret_cast<float2*>(out + (size_t)n * 128 + 2 * lane) = make_float2(ox, oy);
}

// ---------------- aggregation, layer 3 (NOUT=188=4*47) + mean + log_softmax ----
__global__ __launch_bounds__(256) void gat_agg_final(const float* __restrict__ feat,
                                                     const float* __restrict__ el,
                                                     const float* __restrict__ er,
                                                     const int* __restrict__ offs,
                                                     const int* __restrict__ csrc,
                                                     float* __restrict__ out) {
    __shared__ float lds[4][188];
    int wave = threadIdx.x >> 6;
    int lane = threadIdx.x & 63;
    int n = blockIdx.x * 4 + wave;
    // slot flat indices: f0=lane, f1=lane+64, f2=lane+128 (lane<60)
    bool b0 = lane >= 47;   // f0 head: 0 or 1
    bool b1 = lane >= 30;   // f1 head: 1 or 2
    bool b2 = lane >= 13;   // f2 head: 2 or 3
    float4 erv = *reinterpret_cast<const float4*>(er + (size_t)n * NH);
    int i0 = offs[n], i1 = offs[n + 1];
    float mA = -__builtin_inff(), mB = mA, mC = mA, mD = mA;
    float sA = 0.f, sB = 0.f, sC = 0.f, sD = 0.f;
    float a0 = 0.f, a1 = 0.f, a2 = 0.f;
    for (int i = i0; i < i1; ++i) {
        int src = csrc[i];
        const float* fr = feat + (size_t)src * 188;
        float v0 = fr[lane];
        float v1 = fr[lane + 64];
        float v2 = (lane < 60) ? fr[lane + 128] : 0.f;
        float4 elv = *reinterpret_cast<const float4*>(el + (size_t)src * NH);
        float e0 = elv.x + erv.x; e0 = e0 >= 0.f ? e0 : 0.2f * e0;
        float e1 = elv.y + erv.y; e1 = e1 >= 0.f ? e1 : 0.2f * e1;
        float e2 = elv.z + erv.z; e2 = e2 >= 0.f ? e2 : 0.2f * e2;
        float e3 = elv.w + erv.w; e3 = e3 >= 0.f ? e3 : 0.2f * e3;
        float mnA = fmaxf(mA, e0), scA = __expf(mA - mnA), pA = __expf(e0 - mnA);
        float mnB = fmaxf(mB, e1), scB = __expf(mB - mnB), pB = __expf(e1 - mnB);
        float mnC = fmaxf(mC, e2), scC = __expf(mC - mnC), pC = __expf(e2 - mnC);
        float mnD = fmaxf(mD, e3), scD = __expf(mD - mnD), pD = __expf(e3 - mnD);
        sA = sA * scA + pA; mA = mnA;
        sB = sB * scB + pB; mB = mnB;
        sC = sC * scC + pC; mC = mnC;
        sD = sD * scD + pD; mD = mnD;
        float p0 = b0 ? pB : pA, sc0 = b0 ? scB : scA;
        float p1 = b1 ? pC : pB, sc1 = b1 ? scC : scB;
        float p2 = b2 ? pD : pC, sc2 = b2 ? scD : scC;
        a0 = fmaf(p0, v0, a0 * sc0);
        a1 = fmaf(p1, v1, a1 * sc1);
        a2 = fmaf(p2, v2, a2 * sc2);
    }
    float s0 = b0 ? sB : sA;
    float s1 = b1 ? sC : sB;
    float s2 = b2 ? sD : sC;
    lds[wave][lane] = (s0 > 0.f) ? a0 / s0 : 0.f;
    lds[wave][lane + 64] = (s1 > 0.f) ? a1 / s1 : 0.f;
    if (lane < 60) lds[wave][lane + 128] = (s2 > 0.f) ? a2 / s2 : 0.f;
    __syncthreads();
    float u = (lane < 47)
                  ? 0.25f * (lds[wave][lane] + lds[wave][47 + lane] +
                             lds[wave][94 + lane] + lds[wave][141 + lane])
                  : -__builtin_inff();
    float mx = u;
#pragma unroll
    for (int o = 32; o > 0; o >>= 1) mx = fmaxf(mx, __shfl_xor(mx, o));
    float ex = (lane < 47) ? __expf(u - mx) : 0.f;
    float sm = ex;
#pragma unroll
    for (int o = 32; o > 0; o >>= 1) sm += __shfl_xor(sm, o);
    if (lane < 47) out[(size_t)n * 47 + lane] = u - mx - logf(sm);
}

// ---------------- launch ----------------

extern "C" void kernel_launch(void* const* d_in, const int* in_sizes, int n_in,
                              void* d_out, int out_size, void* d_ws, size_t ws_size,
                              hipStream_t stream) {
    const float* x = (const float*)d_in[0];
    const int* src = (const int*)d_in[1];
    const int* dst = (const int*)d_in[2];
    const float* W1 = (const float*)d_in[3];
    const float* al1 = (const float*)d_in[4];
    const float* ar1 = (const float*)d_in[5];
    const float* W2 = (const float*)d_in[6];
    const float* al2 = (const float*)d_in[7];
    const float* ar2 = (const float*)d_in[8];
    const float* W3 = (const float*)d_in[9];
    const float* al3 = (const float*)d_in[10];
    const float* ar3 = (const float*)d_in[11];
    float* out = (float*)d_out;

    char* p = (char*)d_ws;
    auto alloc = [&](size_t bytes) {
        char* r = p;
        p += (bytes + 255) & ~(size_t)255;
        return r;
    };
    float* bufA = (float*)alloc((size_t)N_NODES * 128 * 4);
    float* bufB = (float*)alloc((size_t)N_NODES * 188 * 4);
    float* bufC = (float*)alloc((size_t)N_NODES * 128 * 4);
    float* el = (float*)alloc((size_t)N_NODES * NH * 4);
    float* er = (float*)alloc((size_t)N_NODES * NH * 4);
    int* deg = (int*)alloc((size_t)N_NODES * 4);
    int* offs = (int*)alloc((size_t)(N_NODES + 1) * 4);
    int* cursor = (int*)alloc((size_t)N_NODES * 4);
    int* bsum = (int*)alloc(64 * 4);
    int* csrc = (int*)alloc((size_t)N_EDGES * 4);

    // CSR by dst (graph is identical for all 3 layers; rebuild each call for determinism)
    hipMemsetAsync(deg, 0, (size_t)N_NODES * 4, stream);
    k_hist<<<(N_EDGES + 255) / 256, 256, 0, stream>>>(dst, deg);
    k_scan1<<<49, 1024, 0, stream>>>(deg, offs, bsum);
    k_scan2<<<1, 64, 0, stream>>>(bsum, 49);
    k_scan3<<<49, 1024, 0, stream>>>(offs, bsum, cursor);
    k_scatter<<<(N_EDGES + 255) / 256, 256, 0, stream>>>(src, dst, cursor, csrc);

    // layer 1
    gemm_feat<256, 128, 128, 32><<<N_NODES, 128, 0, stream>>>(x, W1, al1, ar1, bufB, el, er);
    gat_agg128<<<N_NODES / 4, 256, 0, stream>>>(bufB, el, er, offs, csrc, bufA);
    // layer 2
    gemm_feat<128, 128, 128, 32><<<N_NODES, 128, 0, stream>>>(bufA, W2, al2, ar2, bufB, el, er);
    gat_agg128<<<N_NODES / 4, 256, 0, stream>>>(bufB, el, er, offs, csrc, bufC);
    // layer 3
    gemm_feat<128, 188, 192, 47><<<N_NODES, 192, 0, stream>>>(bufC, W3, al3, ar3, bufB, el, er);
    gat_agg_final<<<N_NODES / 4, 256, 0, stream>>>(bufB, el, er, offs, csrc, out);
}

// Round 2
// 580.243 us; speedup vs baseline: 1.5993x; 1.5993x over previous
//
#include <hip/hip_runtime.h>
#include <hip/hip_bf16.h>
#include <math.h>

#define N_NODES 50000
#define N_EDGES 800000
#define NH 4

// ---------------- CSR build ----------------

__global__ void k_hist(const int* __restrict__ dst, int* __restrict__ deg) {
    int i = blockIdx.x * 256 + threadIdx.x;
    if (i < N_EDGES) atomicAdd(&deg[dst[i]], 1);
}

__global__ __launch_bounds__(1024) void k_scan1(const int* __restrict__ deg,
                                                int* __restrict__ offs,
                                                int* __restrict__ bsum) {
    __shared__ int tmp[1024];
    int b = blockIdx.x, t = threadIdx.x;
    int i = b * 1024 + t;
    int v = (i < N_NODES) ? deg[i] : 0;
    tmp[t] = v;
    __syncthreads();
    for (int off = 1; off < 1024; off <<= 1) {
        int add = (t >= off) ? tmp[t - off] : 0;
        __syncthreads();
        tmp[t] += add;
        __syncthreads();
    }
    if (i < N_NODES) offs[i] = tmp[t] - v;   // exclusive within block
    if (t == 1023) bsum[b] = tmp[t];
}

__global__ void k_scan2(int* __restrict__ bsum, int nb) {
    if (blockIdx.x == 0 && threadIdx.x == 0) {
        int run = 0;
        for (int b = 0; b < nb; ++b) { int v = bsum[b]; bsum[b] = run; run += v; }
    }
}

__global__ __launch_bounds__(1024) void k_scan3(int* __restrict__ offs,
                                                const int* __restrict__ bsum,
                                                int* __restrict__ cursor) {
    int b = blockIdx.x, t = threadIdx.x;
    int i = b * 1024 + t;
    if (i < N_NODES) {
        int o = offs[i] + bsum[b];
        offs[i] = o;
        cursor[i] = o;
    }
    if (b == 0 && t == 0) offs[N_NODES] = N_EDGES;
}

__global__ void k_scatter(const int* __restrict__ src, const int* __restrict__ dst,
                          int* __restrict__ cursor, int* __restrict__ csrc) {
    int i = blockIdx.x * 256 + threadIdx.x;
    if (i < N_EDGES) {
        int p = atomicAdd(&cursor[dst[i]], 1);
        csrc[p] = src[i];
    }
}

// ---------------- tiled GEMM: feat = A @ W ----------------
// BM rows x NOUT cols per block; BK=32 K-staging in LDS; 4x8 micro-tile/thread.
// NP = NOUT padded to /8 (192 for 188). NT = (BM/4) * (NP/8).
template <int K, int NOUT, int NP, int BM, int NT>
__global__ __launch_bounds__(NT) void gemm_tiled(const float* __restrict__ A,
                                                 const float* __restrict__ W,
                                                 float* __restrict__ feat) {
    constexpr int BK = 32;
    constexpr int NSTRIP = NP / 8;
    __shared__ float lds_a[BK][BM + 4];   // +4 pad keeps 16B alignment, spreads banks
    __shared__ float lds_b[BK][NP];
    int tid = threadIdx.x;
    int rs = tid / NSTRIP, cs = tid % NSTRIP;
    int row0 = rs * 4, col0 = cs * 8;
    int m0 = blockIdx.x * BM;
    float acc[4][8];
#pragma unroll
    for (int i = 0; i < 4; ++i)
#pragma unroll
        for (int j = 0; j < 8; ++j) acc[i][j] = 0.f;

    for (int kb = 0; kb < K; kb += BK) {
        // stage A tile (transposed): lds_a[k][row]
        for (int idx = tid; idx < BM * (BK / 4); idx += NT) {
            int r = idx >> 3;       // BK/4 == 8
            int c4 = idx & 7;
            int gr = m0 + r;
            float4 v = make_float4(0.f, 0.f, 0.f, 0.f);
            if (gr < N_NODES)
                v = *reinterpret_cast<const float4*>(A + (size_t)gr * K + kb + c4 * 4);
            lds_a[c4 * 4 + 0][r] = v.x;
            lds_a[c4 * 4 + 1][r] = v.y;
            lds_a[c4 * 4 + 2][r] = v.z;
            lds_a[c4 * 4 + 3][r] = v.w;
        }
        // stage B tile: lds_b[k][col]
        constexpr int NV4 = NOUT / 4;   // 32 or 47 (rows are 16B aligned since NOUT%4==0)
        for (int idx = tid; idx < BK * NV4; idx += NT) {
            int r = idx / NV4, c = idx % NV4;
            float4 v = *reinterpret_cast<const float4*>(W + (size_t)(kb + r) * NOUT + c * 4);
            *reinterpret_cast<float4*>(&lds_b[r][c * 4]) = v;
        }
        __syncthreads();
#pragma unroll
        for (int kk = 0; kk < BK; ++kk) {
            float4 a = *reinterpret_cast<const float4*>(&lds_a[kk][row0]);
            float4 b0 = *reinterpret_cast<const float4*>(&lds_b[kk][col0]);
            float4 b1 = *reinterpret_cast<const float4*>(&lds_b[kk][col0 + 4]);
            float av[4] = {a.x, a.y, a.z, a.w};
            float bv[8] = {b0.x, b0.y, b0.z, b0.w, b1.x, b1.y, b1.z, b1.w};
#pragma unroll
            for (int i = 0; i < 4; ++i)
#pragma unroll
                for (int j = 0; j < 8; ++j) acc[i][j] = fmaf(av[i], bv[j], acc[i][j]);
        }
        __syncthreads();
    }
    // store
#pragma unroll
    for (int i = 0; i < 4; ++i) {
        int n = m0 + row0 + i;
        if (n >= N_NODES) break;
        float4 v0 = make_float4(acc[i][0], acc[i][1], acc[i][2], acc[i][3]);
        float4 v1 = make_float4(acc[i][4], acc[i][5], acc[i][6], acc[i][7]);
        if (col0 + 4 <= NOUT)
            *reinterpret_cast<float4*>(feat + (size_t)n * NOUT + col0) = v0;
        if (col0 + 8 <= NOUT)
            *reinterpret_cast<float4*>(feat + (size_t)n * NOUT + col0 + 4) = v1;
    }
}

// ---------------- attention dots: el/er = sum_d feat*a ----------------
template <int NOUT, int DH>
__global__ __launch_bounds__(256) void attn_dots(const float* __restrict__ feat,
                                                 const float* __restrict__ al,
                                                 const float* __restrict__ ar,
                                                 float* __restrict__ el,
                                                 float* __restrict__ er) {
    int wave = threadIdx.x >> 6, lane = threadIdx.x & 63;
    int n = blockIdx.x * 4 + wave;
    int h = lane >> 4, t = lane & 15;
    const float* f = feat + (size_t)n * NOUT + h * DH;
    const float* alh = al + h * DH;
    const float* arh = ar + h * DH;
    float sl = 0.f, sr = 0.f;
#pragma unroll
    for (int d0 = 0; d0 < DH; d0 += 16) {
        int d = d0 + t;
        if (d < DH) {
            float fv = f[d];
            sl = fmaf(fv, alh[d], sl);
            sr = fmaf(fv, arh[d], sr);
        }
    }
#pragma unroll
    for (int o = 1; o < 16; o <<= 1) {
        sl += __shfl_xor(sl, o);
        sr += __shfl_xor(sr, o);
    }
    if (t == 0) { el[n * NH + h] = sl; er[n * NH + h] = sr; }
}

// ---------------- aggregation, layers 1-2 (NOUT=128) ----------------
__global__ __launch_bounds__(256) void gat_agg128(const float* __restrict__ feat,
                                                  const float* __restrict__ el,
                                                  const float* __restrict__ er,
                                                  const int* __restrict__ offs,
                                                  const int* __restrict__ csrc,
                                                  float* __restrict__ out) {
    int wave = threadIdx.x >> 6;
    int lane = threadIdx.x & 63;
    int n = blockIdx.x * 4 + wave;
    int h = lane >> 4;
    float erh = er[n * NH + h];
    int i0 = offs[n], i1 = offs[n + 1];
    float m = -__builtin_inff(), s = 0.f, ax = 0.f, ay = 0.f;
    for (int i = i0; i < i1; ++i) {
        int src = csrc[i];
        float2 v = *reinterpret_cast<const float2*>(feat + (size_t)src * 128 + 2 * lane);
        float e = el[src * NH + h] + erh;
        e = e >= 0.f ? e : 0.2f * e;
        float mn = fmaxf(m, e);
        float sc = __expf(m - mn);
        float p = __expf(e - mn);
        s = s * sc + p;
        ax = fmaf(p, v.x, ax * sc);
        ay = fmaf(p, v.y, ay * sc);
        m = mn;
    }
    float inv = (s > 0.f) ? 1.f / s : 0.f;
    float ox = ax * inv, oy = ay * inv;
    ox = ox > 0.f ? ox : expm1f(ox);
    oy = oy > 0.f ? oy : expm1f(oy);
    *reinterpret_cast<float2*>(out + (size_t)n * 128 + 2 * lane) = make_float2(ox, oy);
}

// ---------------- aggregation, layer 3 (NOUT=188) + mean + log_softmax ----
__global__ __launch_bounds__(256) void gat_agg_final(const float* __restrict__ feat,
                                                     const float* __restrict__ el,
                                                     const float* __restrict__ er,
                                                     const int* __restrict__ offs,
                                                     const int* __restrict__ csrc,
                                                     float* __restrict__ out) {
    __shared__ float lds[4][188];
    int wave = threadIdx.x >> 6;
    int lane = threadIdx.x & 63;
    int n = blockIdx.x * 4 + wave;
    bool b0 = lane >= 47;
    bool b1 = lane >= 30;
    bool b2 = lane >= 13;
    float4 erv = *reinterpret_cast<const float4*>(er + (size_t)n * NH);
    int i0 = offs[n], i1 = offs[n + 1];
    float mA = -__builtin_inff(), mB = mA, mC = mA, mD = mA;
    float sA = 0.f, sB = 0.f, sC = 0.f, sD = 0.f;
    float a0 = 0.f, a1 = 0.f, a2 = 0.f;
    for (int i = i0; i < i1; ++i) {
        int src = csrc[i];
        const float* fr = feat + (size_t)src * 188;
        float v0 = fr[lane];
        float v1 = fr[lane + 64];
        float v2 = (lane < 60) ? fr[lane + 128] : 0.f;
        float4 elv = *reinterpret_cast<const float4*>(el + (size_t)src * NH);
        float e0 = elv.x + erv.x; e0 = e0 >= 0.f ? e0 : 0.2f * e0;
        float e1 = elv.y + erv.y; e1 = e1 >= 0.f ? e1 : 0.2f * e1;
        float e2 = elv.z + erv.z; e2 = e2 >= 0.f ? e2 : 0.2f * e2;
        float e3 = elv.w + erv.w; e3 = e3 >= 0.f ? e3 : 0.2f * e3;
        float mnA = fmaxf(mA, e0), scA = __expf(mA - mnA), pA = __expf(e0 - mnA);
        float mnB = fmaxf(mB, e1), scB = __expf(mB - mnB), pB = __expf(e1 - mnB);
        float mnC = fmaxf(mC, e2), scC = __expf(mC - mnC), pC = __expf(e2 - mnC);
        float mnD = fmaxf(mD, e3), scD = __expf(mD - mnD), pD = __expf(e3 - mnD);
        sA = sA * scA + pA; mA = mnA;
        sB = sB * scB + pB; mB = mnB;
        sC = sC * scC + pC; mC = mnC;
        sD = sD * scD + pD; mD = mnD;
        float p0 = b0 ? pB : pA, sc0 = b0 ? scB : scA;
        float p1 = b1 ? pC : pB, sc1 = b1 ? scC : scB;
        float p2 = b2 ? pD : pC, sc2 = b2 ? scD : scC;
        a0 = fmaf(p0, v0, a0 * sc0);
        a1 = fmaf(p1, v1, a1 * sc1);
        a2 = fmaf(p2, v2, a2 * sc2);
    }
    float s0 = b0 ? sB : sA;
    float s1 = b1 ? sC : sB;
    float s2 = b2 ? sD : sC;
    lds[wave][lane] = (s0 > 0.f) ? a0 / s0 : 0.f;
    lds[wave][lane + 64] = (s1 > 0.f) ? a1 / s1 : 0.f;
    if (lane < 60) lds[wave][lane + 128] = (s2 > 0.f) ? a2 / s2 : 0.f;
    __syncthreads();
    float u = (lane < 47)
                  ? 0.25f * (lds[wave][lane] + lds[wave][47 + lane] +
                             lds[wave][94 + lane] + lds[wave][141 + lane])
                  : -__builtin_inff();
    float mx = u;
#pragma unroll
    for (int o = 32; o > 0; o >>= 1) mx = fmaxf(mx, __shfl_xor(mx, o));
    float ex = (lane < 47) ? __expf(u - mx) : 0.f;
    float sm = ex;
#pragma unroll
    for (int o = 32; o > 0; o >>= 1) sm += __shfl_xor(sm, o);
    if (lane < 47) out[(size_t)n * 47 + lane] = u - mx - logf(sm);
}

// ---------------- launch ----------------

extern "C" void kernel_launch(void* const* d_in, const int* in_sizes, int n_in,
                              void* d_out, int out_size, void* d_ws, size_t ws_size,
                              hipStream_t stream) {
    const float* x = (const float*)d_in[0];
    const int* src = (const int*)d_in[1];
    const int* dst = (const int*)d_in[2];
    const float* W1 = (const float*)d_in[3];
    const float* al1 = (const float*)d_in[4];
    const float* ar1 = (const float*)d_in[5];
    const float* W2 = (const float*)d_in[6];
    const float* al2 = (const float*)d_in[7];
    const float* ar2 = (const float*)d_in[8];
    const float* W3 = (const float*)d_in[9];
    const float* al3 = (const float*)d_in[10];
    const float* ar3 = (const float*)d_in[11];
    float* out = (float*)d_out;

    char* p = (char*)d_ws;
    auto alloc = [&](size_t bytes) {
        char* r = p;
        p += (bytes + 255) & ~(size_t)255;
        return r;
    };
    float* bufA = (float*)alloc((size_t)N_NODES * 128 * 4);
    float* bufB = (float*)alloc((size_t)N_NODES * 188 * 4);
    float* bufC = (float*)alloc((size_t)N_NODES * 128 * 4);
    float* el = (float*)alloc((size_t)N_NODES * NH * 4);
    float* er = (float*)alloc((size_t)N_NODES * NH * 4);
    int* deg = (int*)alloc((size_t)N_NODES * 4);
    int* offs = (int*)alloc((size_t)(N_NODES + 1) * 4);
    int* cursor = (int*)alloc((size_t)N_NODES * 4);
    int* bsum = (int*)alloc(64 * 4);
    int* csrc = (int*)alloc((size_t)N_EDGES * 4);

    // CSR by dst
    hipMemsetAsync(deg, 0, (size_t)N_NODES * 4, stream);
    k_hist<<<(N_EDGES + 255) / 256, 256, 0, stream>>>(dst, deg);
    k_scan1<<<49, 1024, 0, stream>>>(deg, offs, bsum);
    k_scan2<<<1, 64, 0, stream>>>(bsum, 49);
    k_scan3<<<49, 1024, 0, stream>>>(offs, bsum, cursor);
    k_scatter<<<(N_EDGES + 255) / 256, 256, 0, stream>>>(src, dst, cursor, csrc);

    // layer 1
    gemm_tiled<256, 128, 128, 64, 256><<<(N_NODES + 63) / 64, 256, 0, stream>>>(x, W1, bufB);
    attn_dots<128, 32><<<N_NODES / 4, 256, 0, stream>>>(bufB, al1, ar1, el, er);
    gat_agg128<<<N_NODES / 4, 256, 0, stream>>>(bufB, el, er, offs, csrc, bufA);
    // layer 2
    gemm_tiled<128, 128, 128, 64, 256><<<(N_NODES + 63) / 64, 256, 0, stream>>>(bufA, W2, bufB);
    attn_dots<128, 32><<<N_NODES / 4, 256, 0, stream>>>(bufB, al2, ar2, el, er);
    gat_agg128<<<N_NODES / 4, 256, 0, stream>>>(bufB, el, er, offs, csrc, bufC);
    // layer 3
    gemm_tiled<128, 188, 192, 32, 192><<<(N_NODES + 31) / 32, 192, 0, stream>>>(bufC, W3, bufB);
    attn_dots<188, 47><<<N_NODES / 4, 256, 0, stream>>>(bufB, al3, ar3, el, er);
    gat_agg_final<<<N_NODES / 4, 256, 0, stream>>>(bufB, el, er, offs, csrc, out);
}